// Round 3
// baseline (625.271 us; speedup 1.0000x reference)
//
#include <hip/hip_runtime.h>

// Fused LayerNorm-LSTM cell + zoneout for MI355X (gfx950).
// GEMM: concat(x,h)[65536x512] @ W[512x1024] via mfma_f32_16x16x32_f16,
// fused with block-LN(4x256), gates, LN(new_c), zoneout.
//
// R2 restructure: K-loop is now BARRIER-FREE and LDS-FREE. MFMA fragments are
// 16B-contiguous in global memory (x/h row-major for A, pre-transposed Wt for
// B), so they load straight global->VGPR with 1-iter software prefetch.
// R2 counters showed latency-bound (HBM 15%, Mfma 10%, VALU 27%): 48 barriers
// + vmcnt(0) drains per block dominated. LDS is used only by the epilogue.

#define NTHREADS 512
#define TILE_M 64
#define PRE_STRIDE 20  // halfs per n-row in epilogue scratch (16 rows + 4 pad)

typedef _Float16 half8 __attribute__((ext_vector_type(8)));
typedef _Float16 half4v __attribute__((ext_vector_type(4)));
typedef float float4v __attribute__((ext_vector_type(4)));

__device__ __forceinline__ float sigm(float x) {
  return __fdividef(1.0f, 1.0f + __expf(-x));
}
__device__ __forceinline__ float tanh_fast(float x) {
  return 2.0f * __fdividef(1.0f, 1.0f + __expf(-2.0f * x)) - 1.0f;
}

// ---- Kernel 0: W[512][1024] fp32 -> Wt[1024][512] fp16 (tiled transpose) ----
__global__ __launch_bounds__(256) void wt_kernel(const float* __restrict__ W,
                                                 _Float16* __restrict__ Wt) {
  __shared__ float tile[64][65];
  const int bn = blockIdx.x << 6;  // n block (16)
  const int bk = blockIdx.y << 6;  // k block (8)
  const int tid = threadIdx.x;
#pragma unroll
  for (int i = 0; i < 16; ++i) {
    int idx = (i << 8) + tid;
    int kk = idx >> 6, nn = idx & 63;
    tile[kk][nn] = W[(size_t)(bk + kk) * 1024 + bn + nn];
  }
  __syncthreads();
#pragma unroll
  for (int i = 0; i < 16; ++i) {
    int idx = (i << 8) + tid;
    int nn = idx >> 6, kk = idx & 63;
    Wt[(size_t)(bn + nn) * 512 + bk + kk] = (_Float16)tile[kk][nn];
  }
}

// ---- Main fused kernel ----
// Block: 64 rows x all 1024 cols. 8 waves; wave w owns cols w*64..+63 and
// +512..+575 (cc 0..3 low half, 4..7 high half). No LDS/barriers in K-loop.
__global__ __launch_bounds__(NTHREADS, 2) void lstm_fused(
    const float* __restrict__ x, const float* __restrict__ hin,
    const float* __restrict__ cin, const _Float16* __restrict__ Wt,
    const float* __restrict__ bias, const float* __restrict__ g1,
    const float* __restrict__ b1, const float* __restrict__ g2,
    const float* __restrict__ b2, const float* __restrict__ mhp,
    const float* __restrict__ mcp, float* __restrict__ out) {
  extern __shared__ char smem[];
  _Float16* preT = (_Float16*)smem;  // 40KB, epilogue only

  const int tid = threadIdx.x;
  const int wave = tid >> 6;
  const int lane = tid & 63;
  const int l15 = lane & 15;
  const int quad = lane >> 4;
  const int blockRow = blockIdx.x * TILE_M;

  float4v acc[4][8];
#pragma unroll
  for (int s = 0; s < 4; ++s)
#pragma unroll
    for (int c = 0; c < 8; ++c) acc[s][c] = (float4v){0.f, 0.f, 0.f, 0.f};

  const float* xb = x + (size_t)blockRow * 256;
  const float* hb = hin + (size_t)blockRow * 256;

  // Per-lane fragment offsets (32-bit: everything fits)
  int aoff[4];
#pragma unroll
  for (int s = 0; s < 4; ++s) aoff[s] = (s * 16 + l15) * 256 + quad * 8;
  int wofs[8];
#pragma unroll
  for (int cc = 0; cc < 8; ++cc) {
    int col = ((cc >> 2) << 9) + wave * 64 + ((cc & 3) << 4) + l15;
    wofs[cc] = col * 512 + quad * 8;
  }

  float4v a0[4], a1[4];  // next A fragment, fp32
  half8 wn[8];           // next W fragments

  // prime iter 0 (k-window 0..31 comes from x)
#pragma unroll
  for (int s = 0; s < 4; ++s) {
    const float* p = xb + aoff[s];
    a0[s] = *(const float4v*)p;
    a1[s] = *(const float4v*)(p + 4);
  }
#pragma unroll
  for (int cc = 0; cc < 8; ++cc) wn[cc] = *(const half8*)(Wt + wofs[cc]);

  for (int iter = 0; iter < 16; ++iter) {
    // convert current A to fp16 fragments
    half8 af[4];
#pragma unroll
    for (int s = 0; s < 4; ++s)
      af[s] = (half8){(_Float16)a0[s].x, (_Float16)a0[s].y, (_Float16)a0[s].z,
                      (_Float16)a0[s].w, (_Float16)a1[s].x, (_Float16)a1[s].y,
                      (_Float16)a1[s].z, (_Float16)a1[s].w};
    const int ni = iter + 1;
    const bool more = ni < 16;
    // prefetch next A (x for k<256, h for k>=256)
    if (more) {
      const float* base = (ni < 8) ? xb : hb;
      const int ko = (ni & 7) << 5;
#pragma unroll
      for (int s = 0; s < 4; ++s) {
        const float* p = base + aoff[s] + ko;
        a0[s] = *(const float4v*)p;
        a1[s] = *(const float4v*)(p + 4);
      }
    }
    // MFMAs on low-half cols (uses wn[0..3] loaded last iter)
#pragma unroll
    for (int s = 0; s < 4; ++s)
#pragma unroll
      for (int cc = 0; cc < 4; ++cc)
        acc[s][cc] = __builtin_amdgcn_mfma_f32_16x16x32_f16(af[s], wn[cc], acc[s][cc], 0, 0, 0);
    if (more) {
#pragma unroll
      for (int cc = 0; cc < 4; ++cc)
        wn[cc] = *(const half8*)(Wt + wofs[cc] + ni * 32);
    }
    // MFMAs on high-half cols
#pragma unroll
    for (int s = 0; s < 4; ++s)
#pragma unroll
      for (int cc = 4; cc < 8; ++cc)
        acc[s][cc] = __builtin_amdgcn_mfma_f32_16x16x32_f16(af[s], wn[cc], acc[s][cc], 0, 0, 0);
    if (more) {
#pragma unroll
      for (int cc = 4; cc < 8; ++cc)
        wn[cc] = *(const half8*)(Wt + wofs[cc] + ni * 32);
    }
  }

  // ---- Epilogue: 4 passes of 16 rows (pass p == row-stripe p) ----
  // Fully unrolled so acc[p][*] indices stay compile-time (R1 lesson: dynamic
  // index demoted acc to scratch -> 4.3GB spill traffic).
  float* out_h = out;
  float* out_c = out + (size_t)65536 * 256;
  const int er = tid >> 5;  // row in pass 0..15
  const int et = tid & 31;  // col phase: cols {et, et+32, ..., et+224}

#pragma unroll
  for (int p = 0; p < 4; ++p) {
    __syncthreads();
    // write acc stripe p -> preT (col-major: [n][row]), b64 per 4 rows
#pragma unroll
    for (int c = 0; c < 8; ++c) {
      int n = ((c >> 2) << 9) + wave * 64 + ((c & 3) << 4) + l15;  // D col = lane&15
      float4v a = acc[p][c];
      half4v hv = {(_Float16)a.x, (_Float16)a.y, (_Float16)a.z, (_Float16)a.w};
      *(half4v*)(preT + n * PRE_STRIDE + (quad << 2)) = hv;  // rows quad*4+reg
    }
    __syncthreads();

    const int rg = blockRow + (p << 4) + er;
    // LN1 stats per 256-chunk
    float mean1[4], rstd1[4];
#pragma unroll
    for (int ch = 0; ch < 4; ++ch) {
      float s = 0.f, q = 0.f;
#pragma unroll
      for (int ss = 0; ss < 8; ++ss) {
        int n = (ch << 8) + (ss << 5) + et;
        float v = (float)preT[n * PRE_STRIDE + er] + bias[n];
        s += v;
        q += v * v;
      }
#pragma unroll
      for (int m = 1; m < 32; m <<= 1) {
        s += __shfl_xor(s, m, 32);
        q += __shfl_xor(q, m, 32);
      }
      float mu = s * (1.0f / 256.0f);
      mean1[ch] = mu;
      rstd1[ch] = __frsqrt_rn(q * (1.0f / 256.0f) - mu * mu + 1e-5f);
    }

    float ncp[8], so[8], cv[8];
    float s2 = 0.f, q2 = 0.f;
#pragma unroll
    for (int ss = 0; ss < 8; ++ss) {
      int hc = (ss << 5) + et;
      float iv = ((float)preT[(hc)*PRE_STRIDE + er] + bias[hc] - mean1[0]) * rstd1[0] * g1[hc] + b1[hc];
      float jv = ((float)preT[(256 + hc) * PRE_STRIDE + er] + bias[256 + hc] - mean1[1]) * rstd1[1] * g1[256 + hc] + b1[256 + hc];
      float fv = ((float)preT[(512 + hc) * PRE_STRIDE + er] + bias[512 + hc] - mean1[2]) * rstd1[2] * g1[512 + hc] + b1[512 + hc];
      float ov = ((float)preT[(768 + hc) * PRE_STRIDE + er] + bias[768 + hc] - mean1[3]) * rstd1[3] * g1[768 + hc] + b1[768 + hc];
      float cval = cin[(size_t)rg * 256 + hc];
      float nc = cval * sigm(fv + 1.0f) + sigm(iv) * tanh_fast(jv);
      ncp[ss] = nc;
      so[ss] = sigm(ov);
      cv[ss] = cval;
      s2 += nc;
      q2 += nc * nc;
    }
#pragma unroll
    for (int m = 1; m < 32; m <<= 1) {
      s2 += __shfl_xor(s2, m, 32);
      q2 += __shfl_xor(q2, m, 32);
    }
    float mu2 = s2 * (1.0f / 256.0f);
    float rstd2 = __frsqrt_rn(q2 * (1.0f / 256.0f) - mu2 * mu2 + 1e-5f);
#pragma unroll
    for (int ss = 0; ss < 8; ++ss) {
      int hc = (ss << 5) + et;
      size_t gi = (size_t)rg * 256 + hc;
      float ncn = (ncp[ss] - mu2) * rstd2 * g2[hc] + b2[hc];
      float nh = tanh_fast(ncn) * so[ss];
      float hval = hin[gi];
      out_h[gi] = (mhp[gi] < 0.7f) ? nh : hval;   // zoneout: mask<keep -> new
      out_c[gi] = (mcp[gi] < 0.7f) ? ncn : cv[ss];
    }
  }
}

extern "C" void kernel_launch(void* const* d_in, const int* in_sizes, int n_in,
                              void* d_out, int out_size, void* d_ws, size_t ws_size,
                              hipStream_t stream) {
  (void)in_sizes; (void)n_in; (void)out_size; (void)ws_size;
  const float* x = (const float*)d_in[0];
  const float* h = (const float*)d_in[1];
  const float* c = (const float*)d_in[2];
  const float* W = (const float*)d_in[3];
  const float* bias = (const float*)d_in[4];
  const float* g1 = (const float*)d_in[5];
  const float* b1 = (const float*)d_in[6];
  const float* g2 = (const float*)d_in[7];
  const float* b2 = (const float*)d_in[8];
  const float* mh = (const float*)d_in[9];
  const float* mc = (const float*)d_in[10];
  _Float16* Wt = (_Float16*)d_ws;  // 1 MB

  wt_kernel<<<dim3(16, 8), dim3(256), 0, stream>>>(W, Wt);
  lstm_fused<<<dim3(1024), dim3(NTHREADS), 40960, stream>>>(
      x, h, c, Wt, bias, g1, b1, g2, b2, mh, mc, (float*)d_out);
}